// Round 10
// baseline (643.272 us; speedup 1.0000x reference)
//
#include <hip/hip_runtime.h>
#include <hip/hip_bf16.h>

#define B_N 128
#define T_N 2048
#define H_N 512

typedef __attribute__((ext_vector_type(8))) short bf16x8;   // 8 bf16 = 4 VGPRs
typedef __attribute__((ext_vector_type(4))) float f32x4;    // MFMA acc

union U4 { unsigned int i[4]; bf16x8 v; };

// RNE f32 -> bf16 (low 16 bits)
__device__ __forceinline__ unsigned int f2bf(float f) {
    unsigned int u = __float_as_uint(f);
    u += 0x7fffu + ((u >> 16) & 1u);
    return u >> 16;
}

// packed f32x2 -> bf16x2 (RNE), single VALU inst
__device__ __forceinline__ unsigned int cvtpk(float lo, float hi) {
    unsigned int r;
    asm("v_cvt_pk_bf16_f32 %0, %1, %2" : "=v"(r) : "v"(lo), "v"(hi));
    return r;
}

// x >= 0 always here (relu+relu)
__device__ __forceinline__ float tanh_fast(float x) {
    float e = __expf(2.f * x);
    float r = __builtin_amdgcn_rcpf(e + 1.f);
    return 1.f - 2.f * r;
}

#define SCHED0 __builtin_amdgcn_sched_barrier(0)

// ---------------------------------------------------------------------------
// K2: w2 (512x512 f32) -> bf16, pre-swizzled within each 1024B row:
// dst_byte(g,k) = g*1024 + ((k*2) ^ ((g&7)<<4)). XOR stays inside each 128B
// k-slice; staged LINEARLY into LDS; fragment read applies byte^((g&7)<<4),
// cancelling (even swizzle count along the path).
// ---------------------------------------------------------------------------
__global__ void k_w2prep(const float* __restrict__ w2, unsigned short* __restrict__ w2sw) {
    int c = blockIdx.x * 256 + threadIdx.x;      // 32768 chunks of 8 elems
    int g = c >> 6, kc = c & 63;
    const float4* s = reinterpret_cast<const float4*>(w2 + (size_t)g * H_N + kc * 8);
    float4 f0 = s[0], f1 = s[1];
    uint4 p;
    p.x = f2bf(f0.x) | (f2bf(f0.y) << 16);
    p.y = f2bf(f0.z) | (f2bf(f0.w) << 16);
    p.z = f2bf(f1.x) | (f2bf(f1.y) << 16);
    p.w = f2bf(f1.z) | (f2bf(f1.w) << 16);
    *reinterpret_cast<uint4*>(reinterpret_cast<char*>(w2sw) + (size_t)g * 1024 +
                              (((kc * 16) ^ ((g & 7) << 4)))) = p;
}

// ---------------------------------------------------------------------------
// K1: q_h[b][g] = relu(query[b]·w1[g])   (f32, tiny; w1 L2-resident)
// ---------------------------------------------------------------------------
__global__ void k_qh(const float* __restrict__ query, const float* __restrict__ w1,
                     float* __restrict__ qh) {
    int b = blockIdx.x;
    int g = threadIdx.x;                          // 512 threads
    __shared__ float q[H_N];
    q[g] = query[(size_t)b * H_N + g];
    __syncthreads();
    const float4* w = reinterpret_cast<const float4*>(w1 + (size_t)g * H_N);
    float acc = 0.f;
#pragma unroll 4
    for (int i = 0; i < H_N / 4; ++i) {
        float4 wv = w[i];
        acc += q[4*i] * wv.x + q[4*i+1] * wv.y + q[4*i+2] * wv.z + q[4*i+3] * wv.w;
    }
    qh[(size_t)b * H_N + g] = fmaxf(acc, 0.f);
}

// ---------------------------------------------------------------------------
// K3 (fused): per block of 64 t-rows (grid 32 x 128):
//   s_t = sum_g w_out[g]*tanh(qh[b][g] + relu(key[b][t]·w2[g]))  -> w_t=exp(s_t)
//   psum[b][c] = sum_t w_t ;  partial[b][c][h] = sum_t w_t * key[t][h]
// GEMM: BM=64, 2 g-sweeps of BN=256, BK=64, 16 steps (k-slice = s&7 !).
// 8 waves 2wr x 4wc, wave tile 32t x 64g, acc[2][4] = 32 regs/lane.
//   A (key): NO LDS — each lane loads its OWN fragment pair (2 x dwordx4 =
//     8 consecutive f32) straight from global (L2/L3-hot after sweep 0),
//     converts via cvt_pk, feeds MFMA.
//   B (w2sw, L2): 256x64 bf16 tiles, 2x32KB LDS dbuf via global_load_lds
//     (linear copy of pre-swizzled slices), staged 1 step ahead.
// Per step: [A loads (8)] SCHED0 [STAGE_B(s+1) (4)] SCHED0 [cvt+MFMA]
// __syncthreads(). A-loads issued BEFORE B so compiler's A-waits leave B in
// flight; barrier's vmcnt(0) makes B(s+1) ready for the next step.
// LDS ~67KB -> 2 blocks/CU, 4 waves/SIMD: TLP hides latency.
// [R9 bugfix]: A k-slice offset was (s<<8); for s>=8 that over-ran the row
// (wrong data) and the final block's reads ran past the end of key -> abort.
// Correct: ((s&7)<<8).
// ---------------------------------------------------------------------------
__global__ __launch_bounds__(512, 4) void k_scores(
    const float* __restrict__ key, const unsigned short* __restrict__ w2sw,
    const float* __restrict__ qh, const float* __restrict__ w_out,
    float* __restrict__ partial, float* __restrict__ psum)
{
    const int b    = blockIdx.y;
    const int chnk = blockIdx.x;
    const int t0   = chnk * 64;
    const int tid  = threadIdx.x;
    const int wid  = tid >> 6;
    const int lane = tid & 63;
    const int lrow = lane & 15;        // fragment row/col
    const int lq   = lane >> 4;        // 0..3 k-group
    const int wr   = wid >> 2;         // 0..1 t half (32 rows)
    const int wc   = wid & 3;          // 0..3 g quarter (64 g of 256)
    const int swzB = (lrow & 7) << 4;  // byte XOR for B fragment reads

    __shared__ __align__(16) char Bbuf[65536];   // 2 x 256rows x 128B k-slice
    __shared__ float sscore[4][64];
    __shared__ float wlds[64];

    const char* keybB = reinterpret_cast<const char*>(key + ((size_t)b * T_N + t0) * H_N);
    const char* w2sb  = reinterpret_cast<const char*>(w2sw);

    // per-lane A row base (m=0); m=1 adds 16 rows = 32768 B
    const char* arow0 = keybB + (size_t)(wr * 32 + lrow) * 2048;

    // B tile u: g rows [(u>>3)*256,+256), bf16 k slice [(u&7)*64,+64) -> buf u&1
#define STAGE_B(u) do {                                          \
        char* dstB_ = Bbuf + (((u) & 1) << 15);                  \
        const char* srcB_ = w2sb + (((u) >> 3) << 18) + (((u) & 7) << 7); \
        _Pragma("unroll")                                        \
        for (int i_ = 0; i_ < 4; ++i_) {                         \
            int c0_ = i_ * 512 + wid * 64;                       \
            int c_  = c0_ + lane;                                \
            int row_ = c_ >> 3, slot_ = c_ & 7;                  \
            __builtin_amdgcn_global_load_lds(                    \
                (const __attribute__((address_space(1))) void*)(srcB_ + (size_t)row_ * 1024 + slot_ * 16), \
                (__attribute__((address_space(3))) void*)(dstB_ + c0_ * 16), 16, 0, 0); \
        }                                                        \
    } while (0)

    f32x4 acc[2][4];
#pragma unroll
    for (int m = 0; m < 2; ++m)
#pragma unroll
        for (int n = 0; n < 4; ++n) acc[m][n] = f32x4{0.f, 0.f, 0.f, 0.f};
    float pscore[2][4] = {};        // [m][r] partials over all g

    // epilogue for one 256-g sweep; loads its constants inline (L2-hot)
#define EPILOG(sw) do {                                                       \
        _Pragma("unroll")                                                     \
        for (int n_ = 0; n_ < 4; ++n_) {                                      \
            int g_ = (sw) * 256 + wc * 64 + n_ * 16 + lrow;                   \
            float wo_ = w_out[g_];                                            \
            float qv_ = qh[(size_t)b * H_N + g_];                             \
            _Pragma("unroll")                                                 \
            for (int m_ = 0; m_ < 2; ++m_) {                                  \
                _Pragma("unroll")                                             \
                for (int r_ = 0; r_ < 4; ++r_) {                              \
                    float x_ = qv_ + fmaxf(acc[m_][n_][r_], 0.f);             \
                    pscore[m_][r_] = fmaf(wo_, tanh_fast(x_), pscore[m_][r_]);\
                }                                                             \
                acc[m_][n_] = f32x4{0.f, 0.f, 0.f, 0.f};                      \
            }                                                                 \
        }                                                                     \
    } while (0)

    STAGE_B(0);
    __syncthreads();          // B(0) landed (vmcnt drain at barrier)

#pragma unroll 1
    for (int s = 0; s < 16; ++s) {
        // ---- A fragment loads FIRST (so A-waits leave B's glds in flight) ----
        float4 fA[2][2][2];   // [m][ksub][half]
#pragma unroll
        for (int m = 0; m < 2; ++m)
#pragma unroll
            for (int ks = 0; ks < 2; ++ks) {
                const char* p = arow0 + m * 32768 + ((s & 7) << 8) + (ks << 7) + (lq << 5);
                fA[m][ks][0] = *reinterpret_cast<const float4*>(p);
                fA[m][ks][1] = *reinterpret_cast<const float4*>(p + 16);
            }
        SCHED0;
        if (s < 15) STAGE_B(s + 1);
        SCHED0;

        // ---- compute step s: B from LDS buf s&1, A from regs ----
        const char* Bcur = Bbuf + ((s & 1) << 15);
#pragma unroll
        for (int ks = 0; ks < 2; ++ks) {
            bf16x8 bv[4];
#pragma unroll
            for (int n = 0; n < 4; ++n) {
                int row = wc * 64 + n * 16 + lrow;
                bv[n] = *reinterpret_cast<const bf16x8*>(
                    Bcur + row * 128 + ((ks * 64 + lq * 16) ^ swzB));
            }
#pragma unroll
            for (int m = 0; m < 2; ++m) {
                U4 u;
                u.i[0] = cvtpk(fA[m][ks][0].x, fA[m][ks][0].y);
                u.i[1] = cvtpk(fA[m][ks][0].z, fA[m][ks][0].w);
                u.i[2] = cvtpk(fA[m][ks][1].x, fA[m][ks][1].y);
                u.i[3] = cvtpk(fA[m][ks][1].z, fA[m][ks][1].w);
#pragma unroll
                for (int n = 0; n < 4; ++n)
                    acc[m][n] = __builtin_amdgcn_mfma_f32_16x16x32_bf16(
                        u.v, bv[n], acc[m][n], 0, 0, 0);
            }
        }
        __syncthreads();      // all reads of buf s&1 done; B(s+1) landed

        if (s == 7) EPILOG(0);
    }
    EPILOG(1);

    // ---- cross-lane (16 g-cols) then cross-wave (4 wc) score reduction ----
#pragma unroll
    for (int m = 0; m < 2; ++m)
#pragma unroll
        for (int r = 0; r < 4; ++r) {
            float v = pscore[m][r];
            v += __shfl_xor(v, 1);
            v += __shfl_xor(v, 2);
            v += __shfl_xor(v, 4);
            v += __shfl_xor(v, 8);
            if (lrow == 0)
                sscore[wc][wr * 32 + m * 16 + lq * 4 + r] = v;
        }
    __syncthreads();

    // ---- w_t = exp(s_t) (no max-sub: |s| <= Sum|w_out| ~ 18, exact shift) ----
    if (tid < 64)
        wlds[tid] = __expf(sscore[0][tid] + sscore[1][tid] +
                           sscore[2][tid] + sscore[3][tid]);
    __syncthreads();

    // ---- psum (wave 0) ----
    if (wid == 0) {
        float v = wlds[lane];
        v += __shfl_xor(v, 1);
        v += __shfl_xor(v, 2);
        v += __shfl_xor(v, 4);
        v += __shfl_xor(v, 8);
        v += __shfl_xor(v, 16);
        v += __shfl_xor(v, 32);
        if (lane == 0) psum[b * 32 + chnk] = v;
    }

    // ---- PV tail: partial[h] = sum_t w_t * key[t][h]; key tile L2-hot ----
    {
        const float* keyp = key + ((size_t)b * T_N + t0) * H_N + tid;
        float a0 = 0.f;
#pragma unroll 8
        for (int t = 0; t < 64; ++t)
            a0 = fmaf(wlds[t], keyp[(size_t)t * H_N], a0);
        partial[((size_t)(b * 32 + chnk)) * H_N + tid] = a0;
    }

#undef STAGE_B
#undef EPILOG
}

// ---------------------------------------------------------------------------
// K4: out[b][h] = (sum_c partial[b][c][h]) / (sum_c psum[b][c])
// ---------------------------------------------------------------------------
__global__ void k_out(const float* __restrict__ partial, const float* __restrict__ psum,
                      float* __restrict__ out) {
    int idx = blockIdx.x * 256 + threadIdx.x;   // 65536 outputs
    int b = idx >> 9, h = idx & 511;
    float s = 0.f, d = 0.f;
#pragma unroll
    for (int c = 0; c < 32; ++c) {
        s += partial[((size_t)(b * 32 + c)) * H_N + h];
        d += psum[b * 32 + c];
    }
    out[idx] = s / d;
}

extern "C" void kernel_launch(void* const* d_in, const int* in_sizes, int n_in,
                              void* d_out, int out_size, void* d_ws, size_t ws_size,
                              hipStream_t stream) {
    const float* query = (const float*)d_in[0];
    const float* key   = (const float*)d_in[1];
    const float* w1    = (const float*)d_in[2];
    const float* w2    = (const float*)d_in[3];
    const float* w_out = (const float*)d_in[4];
    float* out = (float*)d_out;

    char* ws = (char*)d_ws;
    unsigned short* w2sw = (unsigned short*)(ws);            // 512 KB
    float* qh      = (float*)(ws + 524288);                  // 256 KB
    float* partial = (float*)(ws + 1048576);                 // 8 MB (128*32*512*4)
    float* psum    = (float*)(ws + 9437184);                 // 16 KB

    hipLaunchKernelGGL(k_w2prep, dim3(128),     dim3(256), 0, stream, w2, w2sw);
    hipLaunchKernelGGL(k_qh,     dim3(128),     dim3(512), 0, stream, query, w1, qh);
    hipLaunchKernelGGL(k_scores, dim3(32, 128), dim3(512), 0, stream,
                       key, w2sw, qh, w_out, partial, psum);
    hipLaunchKernelGGL(k_out,    dim3(256),     dim3(256), 0, stream, partial, psum, out);
}

// Round 11
// 298.646 us; speedup vs baseline: 2.1540x; 2.1540x over previous
//
#include <hip/hip_runtime.h>
#include <hip/hip_bf16.h>

#define B_N 128
#define T_N 2048
#define H_N 512

typedef __attribute__((ext_vector_type(8))) short bf16x8;   // 8 bf16 = 4 VGPRs
typedef __attribute__((ext_vector_type(4))) float f32x4;    // MFMA acc

union U4 { unsigned int i[4]; bf16x8 v; };

// RNE f32 -> bf16 (low 16 bits)
__device__ __forceinline__ unsigned int f2bf(float f) {
    unsigned int u = __float_as_uint(f);
    u += 0x7fffu + ((u >> 16) & 1u);
    return u >> 16;
}

// packed f32x2 -> bf16x2 (RNE), single VALU inst
__device__ __forceinline__ unsigned int cvtpk(float lo, float hi) {
    unsigned int r;
    asm("v_cvt_pk_bf16_f32 %0, %1, %2" : "=v"(r) : "v"(lo), "v"(hi));
    return r;
}

// x >= 0 always here (relu+relu)
__device__ __forceinline__ float tanh_fast(float x) {
    float e = __expf(2.f * x);
    float r = __builtin_amdgcn_rcpf(e + 1.f);
    return 1.f - 2.f * r;
}

#define SCHED0 __builtin_amdgcn_sched_barrier(0)

// ---------------------------------------------------------------------------
// K2: w2 (512x512 f32) -> bf16, pre-swizzled within each 1024B row:
// dst_byte(g,k) = g*1024 + ((k*2) ^ ((g&7)<<4)). XOR stays inside each 128B
// k-slice; staged LINEARLY into LDS; fragment read applies byte^((g&7)<<4),
// cancelling (even swizzle count along the path).
// ---------------------------------------------------------------------------
__global__ void k_w2prep(const float* __restrict__ w2, unsigned short* __restrict__ w2sw) {
    int c = blockIdx.x * 256 + threadIdx.x;      // 32768 chunks of 8 elems
    int g = c >> 6, kc = c & 63;
    const float4* s = reinterpret_cast<const float4*>(w2 + (size_t)g * H_N + kc * 8);
    float4 f0 = s[0], f1 = s[1];
    uint4 p;
    p.x = f2bf(f0.x) | (f2bf(f0.y) << 16);
    p.y = f2bf(f0.z) | (f2bf(f0.w) << 16);
    p.z = f2bf(f1.x) | (f2bf(f1.y) << 16);
    p.w = f2bf(f1.z) | (f2bf(f1.w) << 16);
    *reinterpret_cast<uint4*>(reinterpret_cast<char*>(w2sw) + (size_t)g * 1024 +
                              (((kc * 16) ^ ((g & 7) << 4)))) = p;
}

// ---------------------------------------------------------------------------
// K1: q_h[b][g] = relu(query[b]·w1[g])   (f32, tiny; w1 L2-resident)
// ---------------------------------------------------------------------------
__global__ void k_qh(const float* __restrict__ query, const float* __restrict__ w1,
                     float* __restrict__ qh) {
    int b = blockIdx.x;
    int g = threadIdx.x;                          // 512 threads
    __shared__ float q[H_N];
    q[g] = query[(size_t)b * H_N + g];
    __syncthreads();
    const float4* w = reinterpret_cast<const float4*>(w1 + (size_t)g * H_N);
    float acc = 0.f;
#pragma unroll 4
    for (int i = 0; i < H_N / 4; ++i) {
        float4 wv = w[i];
        acc += q[4*i] * wv.x + q[4*i+1] * wv.y + q[4*i+2] * wv.z + q[4*i+3] * wv.w;
    }
    qh[(size_t)b * H_N + g] = fmaxf(acc, 0.f);
}

// ---------------------------------------------------------------------------
// K3 (fused): per block of 64 t-rows (grid 32 x 128):
//   s_t = sum_g w_out[g]*tanh(qh[b][g] + relu(key[b][t]·w2[g]))  -> w_t=exp(s_t)
//   psum[b][c] = sum_t w_t ;  partial[b][c][h] = sum_t w_t * key[t][h]
// GEMM: BM=64, BN=512 SINGLE sweep (key HBM-read once, epilogue once),
// BK=64, 8 steps. 8 waves 2wr x 4wc, wave tile 32t x 128g, acc[2][8]=64.
//   A (key, HBM): f32->regs issued ONE STEP AHEAD (latency hidden under
//     compute), cvt_pk -> ds_write into r2's measured-0-conflict XOR layout,
//     dbuf 2x8KB.
//   B (w2sw, L2-resident): single 64KB buffer, glds between the two
//     barriers; its L2 latency is the exposed term, hidden by the OTHER
//     resident block (2 blocks/CU).
// LDS = 64K(B) + 16K(A dbuf) = 80KB exactly -> 2 blocks/CU, 4 waves/SIMD.
// The bet (r8 vs r10 lesson): occupancy-driven overlap + LDS-staged A.
// ---------------------------------------------------------------------------
__global__ __launch_bounds__(512, 4) void k_scores(
    const float* __restrict__ key, const unsigned short* __restrict__ w2sw,
    const float* __restrict__ qh, const float* __restrict__ w_out,
    float* __restrict__ partial, float* __restrict__ psum)
{
    const int b    = blockIdx.y;
    const int chnk = blockIdx.x;
    const int t0   = chnk * 64;
    const int tid  = threadIdx.x;
    const int wid  = tid >> 6;
    const int lane = tid & 63;
    const int lrow = lane & 15;        // fragment row/col
    const int lq   = lane >> 4;        // 0..3 k-group
    const int wr   = wid >> 2;         // 0..1 t half (32 rows)
    const int wc   = wid & 3;          // 0..3 g quarter (128 g of 512)
    const int swz  = (lrow & 7) << 4;  // byte XOR for fragment reads

    // [0,64K): B bf16 buffer (512 rows x 128B); [64K,80K): A bf16 dbuf 2x8KB
    __shared__ __align__(16) char smem[81920];
    char* Bbuf  = smem;
    char* Abase = smem + 65536;
    float* sscore = reinterpret_cast<float*>(smem);          // post-loop alias
    float* wlds   = reinterpret_cast<float*>(smem + 2048);   // post-loop alias

    const char* keybB = reinterpret_cast<const char*>(key + ((size_t)b * T_N + t0) * H_N);
    const char* w2sb  = reinterpret_cast<const char*>(w2sw);

    // A staging: thread -> (row = tid>>3, 8 f32 at col (tid&7)*8); 64x64 f32/step
    const int arow = tid >> 3;
    const int acol = tid & 7;
    const char* asrc = keybB + (size_t)arow * 2048 + acol * 32;
    char* adst = Abase + arow * 128 + ((acol * 16) ^ ((arow & 7) << 4));

    float4 rA[2];            // A(s) f32, 8 regs

#define LOAD_A(u) do {                                           \
        const char* p_ = asrc + ((u) << 8);                      \
        rA[0] = *reinterpret_cast<const float4*>(p_);            \
        rA[1] = *reinterpret_cast<const float4*>(p_ + 16);       \
    } while (0)

#define WRITE_A(u) do {                                          \
        U4 u_;                                                   \
        u_.i[0] = cvtpk(rA[0].x, rA[0].y);                       \
        u_.i[1] = cvtpk(rA[0].z, rA[0].w);                       \
        u_.i[2] = cvtpk(rA[1].x, rA[1].y);                       \
        u_.i[3] = cvtpk(rA[1].z, rA[1].w);                       \
        *reinterpret_cast<bf16x8*>(adst + (((u) & 1) << 13)) = u_.v; \
    } while (0)

    // B tile u: all 512 g rows, byte slice [u*128,+128) of pre-swizzled rows
#define STAGE_B(u) do {                                          \
        _Pragma("unroll")                                        \
        for (int i_ = 0; i_ < 8; ++i_) {                         \
            int c0_ = i_ * 512 + wid * 64;                       \
            int c_  = c0_ + lane;                                \
            int row_ = c_ >> 3, slot_ = c_ & 7;                  \
            __builtin_amdgcn_global_load_lds(                    \
                (const __attribute__((address_space(1))) void*)(w2sb + (size_t)row_ * 1024 + ((u) << 7) + slot_ * 16), \
                (__attribute__((address_space(3))) void*)(Bbuf + c0_ * 16), 16, 0, 0); \
        }                                                        \
    } while (0)

    f32x4 acc[2][8];
#pragma unroll
    for (int m = 0; m < 2; ++m)
#pragma unroll
        for (int n = 0; n < 8; ++n) acc[m][n] = f32x4{0.f, 0.f, 0.f, 0.f};

    // ---- prologue: A(0) staged, B(0) staged, drain ----
    LOAD_A(0);
    asm volatile("s_waitcnt vmcnt(0)" ::: "memory");
    WRITE_A(0);
    STAGE_B(0);
    __syncthreads();         // B(0) in LDS, A(0) written

#pragma unroll 1
    for (int s = 0; s < 8; ++s) {
        if (s < 7) LOAD_A(s + 1);       // issue early; lands during compute
        SCHED0;

        // ---- compute step s: A from Abuf[s&1], B slice from Bbuf ----
        const char* Acur = Abase + ((s & 1) << 13);
#pragma unroll
        for (int ks = 0; ks < 2; ++ks) {
            bf16x8 av[2];
#pragma unroll
            for (int m = 0; m < 2; ++m) {
                int row = wr * 32 + m * 16 + lrow;
                av[m] = *reinterpret_cast<const bf16x8*>(
                    Acur + row * 128 + ((ks * 64 + lq * 16) ^ swz));
            }
#pragma unroll
            for (int nh = 0; nh < 2; ++nh) {
                bf16x8 bv[4];
#pragma unroll
                for (int j = 0; j < 4; ++j) {
                    int row = wc * 128 + (nh * 4 + j) * 16 + lrow;
                    bv[j] = *reinterpret_cast<const bf16x8*>(
                        Bbuf + row * 128 + ((ks * 64 + lq * 16) ^ swz));
                }
#pragma unroll
                for (int m = 0; m < 2; ++m)
#pragma unroll
                    for (int j = 0; j < 4; ++j)
                        acc[m][nh * 4 + j] = __builtin_amdgcn_mfma_f32_16x16x32_bf16(
                            av[m], bv[j], acc[m][nh * 4 + j], 0, 0, 0);
            }
        }
        __syncthreads();     // all reads of Bbuf + Abuf[s&1] done; A(s+1) landed

        if (s < 7) {
            STAGE_B(s + 1);  // glds first (head start on L2 latency)
            WRITE_A(s + 1);  // cvt + ds_write overlap the glds
        }
        __syncthreads();     // drains B(s+1) glds + A write visible
    }

    // ---- epilogue: pscore = sum_n w_out*tanh(qh + relu(acc)) ----
    float pscore[2][4] = {};
#pragma unroll
    for (int n = 0; n < 8; ++n) {
        int g = wc * 128 + n * 16 + lrow;
        float wo = w_out[g];
        float qv = qh[(size_t)b * H_N + g];
#pragma unroll
        for (int m = 0; m < 2; ++m)
#pragma unroll
            for (int r = 0; r < 4; ++r) {
                float x = qv + fmaxf(acc[m][n][r], 0.f);
                pscore[m][r] = fmaf(wo, tanh_fast(x), pscore[m][r]);
            }
    }

    // ---- cross-lane (16 g-cols) then cross-wave (4 wc) score reduction ----
#pragma unroll
    for (int m = 0; m < 2; ++m)
#pragma unroll
        for (int r = 0; r < 4; ++r) {
            float v = pscore[m][r];
            v += __shfl_xor(v, 1);
            v += __shfl_xor(v, 2);
            v += __shfl_xor(v, 4);
            v += __shfl_xor(v, 8);
            if (lrow == 0)
                sscore[wc * 64 + wr * 32 + m * 16 + lq * 4 + r] = v;
        }
    __syncthreads();

    // ---- w_t = exp(s_t) (no max-sub: |s| <= Sum|w_out| ~ 18, exact shift) ----
    if (tid < 64)
        wlds[tid] = __expf(sscore[0 * 64 + tid] + sscore[1 * 64 + tid] +
                           sscore[2 * 64 + tid] + sscore[3 * 64 + tid]);
    __syncthreads();

    // ---- psum (wave 0) ----
    if (wid == 0) {
        float v = wlds[lane];
        v += __shfl_xor(v, 1);
        v += __shfl_xor(v, 2);
        v += __shfl_xor(v, 4);
        v += __shfl_xor(v, 8);
        v += __shfl_xor(v, 16);
        v += __shfl_xor(v, 32);
        if (lane == 0) psum[b * 32 + chnk] = v;
    }

    // ---- PV tail: partial[h] = sum_t w_t * key[t][h]; key tile L2-hot ----
    {
        const float* keyp = key + ((size_t)b * T_N + t0) * H_N + tid;
        float a0 = 0.f;
#pragma unroll 8
        for (int t = 0; t < 64; ++t)
            a0 = fmaf(wlds[t], keyp[(size_t)t * H_N], a0);
        partial[((size_t)(b * 32 + chnk)) * H_N + tid] = a0;
    }

#undef LOAD_A
#undef WRITE_A
#undef STAGE_B
}

// ---------------------------------------------------------------------------
// K4: out[b][h] = (sum_c partial[b][c][h]) / (sum_c psum[b][c])
// ---------------------------------------------------------------------------
__global__ void k_out(const float* __restrict__ partial, const float* __restrict__ psum,
                      float* __restrict__ out) {
    int idx = blockIdx.x * 256 + threadIdx.x;   // 65536 outputs
    int b = idx >> 9, h = idx & 511;
    float s = 0.f, d = 0.f;
#pragma unroll
    for (int c = 0; c < 32; ++c) {
        s += partial[((size_t)(b * 32 + c)) * H_N + h];
        d += psum[b * 32 + c];
    }
    out[idx] = s / d;
}

extern "C" void kernel_launch(void* const* d_in, const int* in_sizes, int n_in,
                              void* d_out, int out_size, void* d_ws, size_t ws_size,
                              hipStream_t stream) {
    const float* query = (const float*)d_in[0];
    const float* key   = (const float*)d_in[1];
    const float* w1    = (const float*)d_in[2];
    const float* w2    = (const float*)d_in[3];
    const float* w_out = (const float*)d_in[4];
    float* out = (float*)d_out;

    char* ws = (char*)d_ws;
    unsigned short* w2sw = (unsigned short*)(ws);            // 512 KB
    float* qh      = (float*)(ws + 524288);                  // 256 KB
    float* partial = (float*)(ws + 1048576);                 // 8 MB (128*32*512*4)
    float* psum    = (float*)(ws + 9437184);                 // 16 KB

    hipLaunchKernelGGL(k_w2prep, dim3(128),     dim3(256), 0, stream, w2, w2sw);
    hipLaunchKernelGGL(k_qh,     dim3(128),     dim3(512), 0, stream, query, w1, qh);
    hipLaunchKernelGGL(k_scores, dim3(32, 128), dim3(512), 0, stream,
                       key, w2sw, qh, w_out, partial, psum);
    hipLaunchKernelGGL(k_out,    dim3(256),     dim3(256), 0, stream, partial, psum, out);
}